// Round 7
// baseline (515.813 us; speedup 1.0000x reference)
//
#include <hip/hip_runtime.h>

#define NN 100000
#define EE 1600000
#define NPAD 100032          // NN rounded up to 64-row MFMA tiles
#define NBKT 196             // ceil(NN/512) scatter buckets
#define CAP 9216             // bucket capacity (mean 8192, sigma 90 -> 11 sigma)
#define BN_EPS 1e-5f

using f32x2  = __attribute__((ext_vector_type(2))) float;
using f32x4  = __attribute__((ext_vector_type(4))) float;
using f32x8  = __attribute__((ext_vector_type(8))) float;
using s16x8  = __attribute__((ext_vector_type(8))) short;
using u16x4  = __attribute__((ext_vector_type(4))) unsigned short;
using u16x8  = __attribute__((ext_vector_type(8))) unsigned short;
using bf16x8 = __attribute__((ext_vector_type(8))) __bf16;
typedef unsigned short ushort_t;

__device__ __forceinline__ float bf2f(ushort_t b) {
  union { unsigned u; float f; } x; x.u = ((unsigned)b) << 16; return x.f;
}
__device__ __forceinline__ ushort_t f2bf(float f) {
  union { float f; unsigned u; } x; x.f = f;
  unsigned r = x.u + 0x7fffu + ((x.u >> 16) & 1u);   // RN-even; no NaNs in pipeline
  return (ushort_t)(r >> 16);
}
// accumulate a dword of 2 bf16 into two f32 lanes
__device__ __forceinline__ void acc2(float& A0, float& A1, unsigned v) {
  union { unsigned u; float f; } a, b;
  a.u = v << 16; b.u = v & 0xffff0000u;
  A0 += a.f; A1 += b.f;
}
__device__ __forceinline__ void acc2w(float& A0, float& A1, unsigned v, float w) {
  union { unsigned u; float f; } a, b;
  a.u = v << 16; b.u = v & 0xffff0000u;
  A0 = fmaf(w, a.f, A0); A1 = fmaf(w, b.f, A1);
}

// ---------------- CSR build: fixed-capacity two-level scatter ----------------
__global__ __launch_bounds__(256) void k_bin(const int* __restrict__ src,
                                             const int* __restrict__ dst,
                                             int* __restrict__ gbc,
                                             unsigned* __restrict__ ebuf) {
  __shared__ int hist[NBKT];
  int t = threadIdx.x;
  for (int i = t; i < NBKT; i += 256) hist[i] = 0;
  __syncthreads();
  int base = blockIdx.x * 4096;
  int s[16], d[16];
#pragma unroll
  for (int j = 0; j < 16; j++) {
    int e = base + j * 256 + t;
    if (e < EE) { s[j] = src[e]; d[j] = dst[e]; atomicAdd(&hist[d[j] >> 9], 1); }
    else d[j] = -1;
  }
  __syncthreads();
  for (int i = t; i < NBKT; i += 256) {
    int c = hist[i];
    hist[i] = c ? atomicAdd(&gbc[i], c) : 0;   // reserve in-bucket run
  }
  __syncthreads();
#pragma unroll
  for (int j = 0; j < 16; j++) {
    if (d[j] >= 0) {
      int bkt = d[j] >> 9;
      int pos = atomicAdd(&hist[bkt], 1);
      if (pos < CAP)                            // safety clamp (never hit here)
        ebuf[(size_t)bkt * CAP + pos] = (unsigned)s[j] | ((unsigned)(d[j] & 511) << 17);
    }
  }
}

// scan bucket counts -> ebase; rowptr[NN]=EE; zero BN stats
__global__ void k_bktscan(const int* __restrict__ gbc, int* __restrict__ ebase,
                          int* __restrict__ rowptr, float* __restrict__ stats) {
  __shared__ int sd[256];
  int t = threadIdx.x;
#pragma unroll
  for (int k = 0; k < 3; k++) stats[t + 256 * k] = 0.f;   // 768 floats
  int c = (t < NBKT) ? min(gbc[t], CAP) : 0;
  sd[t] = c; __syncthreads();
  for (int off = 1; off < 256; off <<= 1) {
    int x = 0;
    if (t >= off) x = sd[t - off];
    __syncthreads();
    sd[t] += x;
    __syncthreads();
  }
  if (t < NBKT) ebase[t] = sd[t] - c;          // exclusive
  if (t == NBKT - 1) rowptr[NN] = sd[t];       // == EE
}

// per bucket: LDS degree hist -> LDS scan -> rowptr + fine scatter
__global__ __launch_bounds__(256) void k_fine(const unsigned* __restrict__ ebuf,
                                              const int* __restrict__ gbc,
                                              const int* __restrict__ ebase,
                                              int* __restrict__ rowptr,
                                              int* __restrict__ csr) {
  __shared__ int dcur[512];
  __shared__ int sd[256];
  int b = blockIdx.x, t = threadIdx.x;
  int cnt = min(gbc[b], CAP);
  int eb = ebase[b];
  const unsigned* eb_p = ebuf + (size_t)b * CAP;
  dcur[t] = 0; dcur[t + 256] = 0;
  __syncthreads();
  for (int e = t; e < cnt; e += 256)
    atomicAdd(&dcur[(eb_p[e] >> 17) & 511], 1);
  __syncthreads();
  int a0 = dcur[2 * t], a1 = dcur[2 * t + 1];
  int ps = a0 + a1;
  sd[t] = ps; __syncthreads();
  for (int off = 1; off < 256; off <<= 1) {
    int x = 0;
    if (t >= off) x = sd[t - off];
    __syncthreads();
    sd[t] += x;
    __syncthreads();
  }
  int g0 = eb + sd[t] - ps;                    // global csr start for local node 2t
  dcur[2 * t] = g0; dcur[2 * t + 1] = g0 + a0;
  int n = (b << 9) + 2 * t;
  if (n < NN) rowptr[n] = g0;
  if (n + 1 < NN) rowptr[n + 1] = g0 + a0;
  __syncthreads();
  for (int e = t; e < cnt; e += 256) {
    unsigned v = eb_p[e];
    int pos = atomicAdd(&dcur[(v >> 17) & 511], 1);
    csr[pos] = (int)(v & 0x1FFFFu);
  }
}

// ------- prep: x -> slice-major bf16 hbS[8][NPAD][8] (blocks 0..3124)
//         + W swizzle (blocks 3125..3136) -------
__global__ void k_prep(const float* __restrict__ x, ushort_t* __restrict__ hbS,
                       const float* __restrict__ W1s, const float* __restrict__ W2s,
                       ushort_t* __restrict__ wf) {
  int b = blockIdx.x;
  if (b < 3125) {
    int gid = b * 256 + threadIdx.x;          // < 800000 = NN*8
    int node = gid >> 3, sl = gid & 7;
    const float* xr = x + (size_t)node * 64 + sl * 8;
    f32x4 v0 = *(const f32x4*)xr;
    f32x4 v1 = *(const f32x4*)(xr + 4);
    u16x8 o;
#pragma unroll
    for (int m = 0; m < 4; m++) { o[m] = f2bf(v0[m]); o[m + 4] = f2bf(v1[m]); }
    *(u16x8*)(hbS + ((size_t)sl * NPAD + node) * 8) = o;
  } else {
    int gid = (b - 3125) * 256 + threadIdx.x;
    if (gid >= 3072) return;                  // 6 mats * 2u * 4t * 64 lanes
    int mat = gid >> 9, rem = gid & 511;
    int u = rem >> 8, t = (rem >> 6) & 3, lane = rem & 63;
    const float* W = ((mat & 1) ? W2s : W1s) + (mat >> 1) * 4096;
    ushort_t* o = wf + gid * 8;
#pragma unroll
    for (int j = 0; j < 8; j++) {
      int k = u * 32 + (lane >> 4) * 8 + j;
      int n = t * 16 + (lane & 15);
      o[j] = f2bf(W[k * 64 + n]);
    }
  }
}

// ---------------- k_agg (v7: XCD-resident feature slices) ----------------
// grid = nwin*8; block b: win = b>>3, slice = b&7. blockIdx%8 -> XCD
// (round-robin dispatch heuristic), so slice s's 1.6 MB table stays resident
// in XCD s's 4 MB L2 -> row gathers are L2 hits; fills are compulsory-only.
// 256 thr = 4 waves; 4-lane group owns one node (lane = 2 features, dword
// loads); R2's proven 8-wide masked chunks + csr prefetch-in-dead-regs.
// Output: AGG[node][64] f32 (neighbor sum only; self added in k_mlp1).
__global__ __launch_bounds__(256) void k_agg(
    const ushort_t* __restrict__ hbS, const int* __restrict__ rowptr,
    const int* __restrict__ csr, float* __restrict__ aggf) {
  int b = blockIdx.x;
  int win = b >> 3, sl = b & 7;
  int tid = threadIdx.x;
  int wv = tid >> 6, lane = tid & 63;
  int grp = lane >> 2, fq = lane & 3;
  int node = win * 64 + wv * 16 + grp;
  if (node >= NN) return;                      // no barriers below: safe
  const ushort_t* sb = hbS + (size_t)sl * NPAD * 8 + fq * 2;
  float A0 = 0.f, A1 = 0.f;
  int e = rowptr[node];
  int rem = rowptr[node + 1] - e;
  if (rem >= 8) {
    int s0 = csr[e],     s1 = csr[e + 1], s2 = csr[e + 2], s3 = csr[e + 3];
    int s4 = csr[e + 4], s5 = csr[e + 5], s6 = csr[e + 6], s7 = csr[e + 7];
    for (;;) {
      unsigned r0 = *(const unsigned*)(sb + (size_t)s0 * 8);
      unsigned r1 = *(const unsigned*)(sb + (size_t)s1 * 8);
      unsigned r2 = *(const unsigned*)(sb + (size_t)s2 * 8);
      unsigned r3 = *(const unsigned*)(sb + (size_t)s3 * 8);
      unsigned r4 = *(const unsigned*)(sb + (size_t)s4 * 8);
      unsigned r5 = *(const unsigned*)(sb + (size_t)s5 * 8);
      unsigned r6 = *(const unsigned*)(sb + (size_t)s6 * 8);
      unsigned r7 = *(const unsigned*)(sb + (size_t)s7 * 8);
      e += 8; rem -= 8;
      bool more = (rem >= 8);
      if (more) {                              // prefetch next chunk's indices
        s0 = csr[e];     s1 = csr[e + 1]; s2 = csr[e + 2]; s3 = csr[e + 3];
        s4 = csr[e + 4]; s5 = csr[e + 5]; s6 = csr[e + 6]; s7 = csr[e + 7];
      }
      acc2(A0, A1, r0); acc2(A0, A1, r1); acc2(A0, A1, r2); acc2(A0, A1, r3);
      acc2(A0, A1, r4); acc2(A0, A1, r5); acc2(A0, A1, r6); acc2(A0, A1, r7);
      if (!more) break;
    }
  }
  if (rem > 0) {                               // clamp-masked tail (exact)
    int last = e + rem - 1;
    int s0 = csr[e];
    int s1 = csr[min(e + 1, last)], s2 = csr[min(e + 2, last)];
    int s3 = csr[min(e + 3, last)], s4 = csr[min(e + 4, last)];
    int s5 = csr[min(e + 5, last)], s6 = csr[min(e + 6, last)];
    int s7 = csr[min(e + 7, last)];
    unsigned r0 = *(const unsigned*)(sb + (size_t)s0 * 8);
    unsigned r1 = *(const unsigned*)(sb + (size_t)s1 * 8);
    unsigned r2 = *(const unsigned*)(sb + (size_t)s2 * 8);
    unsigned r3 = *(const unsigned*)(sb + (size_t)s3 * 8);
    unsigned r4 = *(const unsigned*)(sb + (size_t)s4 * 8);
    unsigned r5 = *(const unsigned*)(sb + (size_t)s5 * 8);
    unsigned r6 = *(const unsigned*)(sb + (size_t)s6 * 8);
    unsigned r7 = *(const unsigned*)(sb + (size_t)s7 * 8);
    acc2(A0, A1, r0);
    acc2w(A0, A1, r1, (rem > 1) ? 1.f : 0.f);
    acc2w(A0, A1, r2, (rem > 2) ? 1.f : 0.f);
    acc2w(A0, A1, r3, (rem > 3) ? 1.f : 0.f);
    acc2w(A0, A1, r4, (rem > 4) ? 1.f : 0.f);
    acc2w(A0, A1, r5, (rem > 5) ? 1.f : 0.f);
    acc2w(A0, A1, r6, (rem > 6) ? 1.f : 0.f);
    acc2w(A0, A1, r7, (rem > 7) ? 1.f : 0.f);
  }
  f32x2 o; o[0] = A0; o[1] = A1;
  *(f32x2*)(aggf + (size_t)node * 64 + sl * 8 + fq * 2) = o;
}

// ---------------- k_mlp1: z = (self + agg)@W1 + b1; BN stats; zb bf16 ----
// zb row-interleaves into AGG (stride 128 ushorts = 256B): block reads its
// rows' aggf in phase 1 (barrier) then overwrites their first half as zb.
__global__ __launch_bounds__(256) void k_mlp1(
    const ushort_t* __restrict__ hbS, const float* __restrict__ aggf,
    ushort_t* __restrict__ zbw, const ushort_t* __restrict__ wfrag,
    const float* __restrict__ b1, float* __restrict__ stats) {
  __shared__ __align__(16) ushort_t sw[64 * 72];
  __shared__ float lsum[64], lsq[64];
  int tid = threadIdx.x;
  if (tid < 64) lsum[tid] = 0.f;
  else if (tid < 128) lsq[tid - 64] = 0.f;
  {
    int r = tid >> 2, c0 = (tid & 3) * 16;
    size_t grow = (size_t)blockIdx.x * 64 + r;
    u16x8 z0 = {0, 0, 0, 0, 0, 0, 0, 0}, z1 = z0;
    if (grow < NN) {
      int s0 = c0 >> 3;
      u16x8 h0 = *(const u16x8*)(hbS + ((size_t)s0 * NPAD + grow) * 8);
      u16x8 h1 = *(const u16x8*)(hbS + ((size_t)(s0 + 1) * NPAD + grow) * 8);
      f32x4 a0 = *(const f32x4*)(aggf + grow * 64 + c0);
      f32x4 a1 = *(const f32x4*)(aggf + grow * 64 + c0 + 4);
      f32x4 a2 = *(const f32x4*)(aggf + grow * 64 + c0 + 8);
      f32x4 a3 = *(const f32x4*)(aggf + grow * 64 + c0 + 12);
#pragma unroll
      for (int m = 0; m < 4; m++) {
        z0[m]     = f2bf(bf2f(h0[m])     + a0[m]);
        z0[m + 4] = f2bf(bf2f(h0[m + 4]) + a1[m]);
        z1[m]     = f2bf(bf2f(h1[m])     + a2[m]);
        z1[m + 4] = f2bf(bf2f(h1[m + 4]) + a3[m]);
      }
    }
    *(u16x8*)(sw + r * 72 + c0) = z0;
    *(u16x8*)(sw + r * 72 + c0 + 8) = z1;
  }
  __syncthreads();
  int wv = tid >> 6, lane = tid & 63;
  int quad = lane >> 4, lo = lane & 15;
  s16x8 bfr[2][4];
#pragma unroll
  for (int u = 0; u < 2; u++)
#pragma unroll
    for (int t = 0; t < 4; t++)
      bfr[u][t] = *(const s16x8*)(wfrag + (size_t)((u * 4 + t) * 64 + lane) * 8);
  f32x4 acc[4] = {};
#pragma unroll
  for (int u = 0; u < 2; u++) {
    bf16x8 af = *(const bf16x8*)(sw + (wv * 16 + lo) * 72 + u * 32 + quad * 8);
#pragma unroll
    for (int t = 0; t < 4; t++)
      acc[t] = __builtin_amdgcn_mfma_f32_16x16x32_bf16(
          af, __builtin_bit_cast(bf16x8, bfr[u][t]), acc[t], 0, 0, 0);
  }
  int row0 = blockIdx.x * 64 + wv * 16;
#pragma unroll
  for (int t = 0; t < 4; t++) {
    int col = t * 16 + lo;
    float bb = b1[col];
    float s1 = 0.f, s2 = 0.f;
#pragma unroll
    for (int r = 0; r < 4; r++) {
      int row = row0 + quad * 4 + r;
      if (row < NN) {
        float v = acc[t][r] + bb;
        zbw[(size_t)row * 128 + col] = f2bf(v);
        s1 += v; s2 += v * v;
      }
    }
    atomicAdd(&lsum[col], s1);
    atomicAdd(&lsq[col], s2);
  }
  __syncthreads();
  if (tid < 64) {
    atomicAdd(&stats[tid], lsum[tid]);
    atomicAdd(&stats[64 + tid], lsq[tid]);
  }
}

// relu_out=1 (L0,L1): hbS = relu( relu(zb*a+c)@W2 + b2 )  (slice-major store)
// relu_out=0 (L2):    h -> out+200000 (fp32) AND out[0..2N) = h@Wd + bd
// zb read at stride 128 ushorts (row-interleaved in AGG).
__global__ __launch_bounds__(256) void k_mlp2(
    const ushort_t* __restrict__ zb, const float* __restrict__ stats,
    const float* __restrict__ gamma, const float* __restrict__ beta,
    const ushort_t* __restrict__ wfrag, const float* __restrict__ b2,
    ushort_t* __restrict__ hbS, float* __restrict__ out,
    const float* __restrict__ Wd, const float* __restrict__ bd, int relu_out) {
  __shared__ __align__(16) ushort_t sw[64 * 72];
  __shared__ float abn[64], cbn[64];
  int tid = threadIdx.x;
  if (tid < 64) {   // fused BN finalize
    float inv = 1.f / (float)NN;
    float mu = stats[tid] * inv;
    float var = stats[64 + tid] * inv - mu * mu;
    float a = gamma[tid] * rsqrtf(var + BN_EPS);
    abn[tid] = a;
    cbn[tid] = beta[tid] - mu * a;
  }
  __syncthreads();
  {   // phase 1: BN affine + ReLU on bf16 z -> bf16 tile in LDS
    int r = tid >> 2, c0 = (tid & 3) * 16;
    size_t grow = (size_t)blockIdx.x * 64 + r;     // < NPAD; padded rows masked at store
#pragma unroll
    for (int jj = 0; jj < 16; jj += 8) {
      s16x8 zv = *(const s16x8*)(zb + grow * 128 + c0 + jj);
      f32x4 av0 = *(const f32x4*)(abn + c0 + jj);
      f32x4 av1 = *(const f32x4*)(abn + c0 + jj + 4);
      f32x4 cv0 = *(const f32x4*)(cbn + c0 + jj);
      f32x4 cv1 = *(const f32x4*)(cbn + c0 + jj + 4);
#pragma unroll
      for (int m = 0; m < 4; m++) {
        float v0 = fmaxf(bf2f((ushort_t)zv[m]) * av0[m] + cv0[m], 0.f);
        float v1 = fmaxf(bf2f((ushort_t)zv[m + 4]) * av1[m] + cv1[m], 0.f);
        sw[r * 72 + c0 + jj + m] = f2bf(v0);
        sw[r * 72 + c0 + jj + m + 4] = f2bf(v1);
      }
    }
  }
  __syncthreads();
  int wv = tid >> 6, lane = tid & 63;
  int quad = lane >> 4, lo = lane & 15;

  s16x8 bfr[2][4];
#pragma unroll
  for (int u = 0; u < 2; u++)
#pragma unroll
    for (int t = 0; t < 4; t++)
      bfr[u][t] = *(const s16x8*)(wfrag + (size_t)((u * 4 + t) * 64 + lane) * 8);

  f32x4 acc[4] = {};
#pragma unroll
  for (int u = 0; u < 2; u++) {
    bf16x8 af = *(const bf16x8*)(sw + (wv * 16 + lo) * 72 + u * 32 + quad * 8);
#pragma unroll
    for (int t = 0; t < 4; t++)
      acc[t] = __builtin_amdgcn_mfma_f32_16x16x32_bf16(
          af, __builtin_bit_cast(bf16x8, bfr[u][t]), acc[t], 0, 0, 0);
  }
  int row0 = blockIdx.x * 64 + wv * 16;
  float bbv[4];
#pragma unroll
  for (int t = 0; t < 4; t++) bbv[t] = b2[t * 16 + lo];

  if (relu_out) {
#pragma unroll
    for (int t = 0; t < 4; t++) {
      int col = t * 16 + lo;
      int sl = col >> 3, cf = col & 7;
#pragma unroll
      for (int r = 0; r < 4; r++) {
        int row = row0 + quad * 4 + r;
        if (row < NN)
          hbS[((size_t)sl * NPAD + row) * 8 + cf] =
              f2bf(fmaxf(acc[t][r] + bbv[t], 0.f));
      }
    }
  } else {
    float* outh = out + (size_t)NN * 2;
    float wd0[4], wd1[4];
#pragma unroll
    for (int t = 0; t < 4; t++) {
      wd0[t] = Wd[(t * 16 + lo) * 2];
      wd1[t] = Wd[(t * 16 + lo) * 2 + 1];
    }
    float bd0 = bd[0], bd1 = bd[1];
#pragma unroll
    for (int t = 0; t < 4; t++) {
      int col = t * 16 + lo;
#pragma unroll
      for (int r = 0; r < 4; r++) {
        int row = row0 + quad * 4 + r;
        if (row < NN) outh[(size_t)row * 64 + col] = acc[t][r] + bbv[t];
      }
    }
#pragma unroll
    for (int r = 0; r < 4; r++) {
      float p0 = 0.f, p1 = 0.f;
#pragma unroll
      for (int t = 0; t < 4; t++) {
        float v = acc[t][r] + bbv[t];
        p0 += v * wd0[t]; p1 += v * wd1[t];
      }
#pragma unroll
      for (int o = 1; o < 16; o <<= 1) {   // reduce across the 16 lanes of the quad
        p0 += __shfl_xor(p0, o);
        p1 += __shfl_xor(p1, o);
      }
      int row = row0 + quad * 4 + r;
      if (lo == 0 && row < NN) {
        out[(size_t)row * 2 + 0] = p0 + bd0;
        out[(size_t)row * 2 + 1] = p1 + bd1;
      }
    }
  }
}

extern "C" void kernel_launch(void* const* d_in, const int* in_sizes, int n_in,
                              void* d_out, int out_size, void* d_ws, size_t ws_size,
                              hipStream_t stream) {
  (void)in_sizes; (void)n_in; (void)out_size; (void)ws_size;
  const float* x   = (const float*)d_in[0];
  const int*   ei  = (const int*)d_in[1];
  const float* W1s = (const float*)d_in[2];
  const float* b1s = (const float*)d_in[3];
  const float* gms = (const float*)d_in[4];
  const float* bts = (const float*)d_in[5];
  const float* W2s = (const float*)d_in[6];
  const float* b2s = (const float*)d_in[7];
  const float* Wd  = (const float*)d_in[8];
  const float* bd  = (const float*)d_in[9];
  float* out = (float*)d_out;
  const int* src = ei;
  const int* dst = ei + EE;

  char* w = (char*)d_ws;
  size_t off = 0;
  auto alloc = [&](size_t b) { char* p = w + off; off += (b + 255) & ~(size_t)255; return p; };
  float*    AGG    = (float*)alloc((size_t)NPAD * 64 * 4);      // 25.6 MB f32 agg
                                                                // (zb interleaves; ebuf aliases)
  ushort_t* hbS    = (ushort_t*)alloc((size_t)NPAD * 64 * 2);   // 12.8 MB slice-major bf16
  int*      csr    = (int*)alloc((size_t)EE * 4);               // 6.4 MB
  int*      rowptr = (int*)alloc((size_t)(NN + 1) * 4);
  int*      gbc    = (int*)alloc((size_t)NBKT * 4);
  int*      ebase  = (int*)alloc((size_t)NBKT * 4);
  float*    stats  = (float*)alloc(768 * 4);                    // 3 x [sum|sq|spare]
  ushort_t* wf     = (ushort_t*)alloc((size_t)6 * 512 * 8 * 2); // swizzled W frags
  unsigned* ebuf   = (unsigned*)AGG;  // 196*9216*4 = 7.2 MB, used pre-mlp only
  ushort_t* zbw    = (ushort_t*)AGG;  // zb rows at stride 128 ushorts (256B)

  hipMemsetAsync(gbc, 0, (size_t)NBKT * 4, stream);
  k_bin    <<<(EE + 4095) / 4096, 256, 0, stream>>>(src, dst, gbc, ebuf);
  k_bktscan<<<1, 256, 0, stream>>>(gbc, ebase, rowptr, stats);
  k_fine   <<<NBKT, 256, 0, stream>>>(ebuf, gbc, ebase, rowptr, csr);
  k_prep   <<<3137, 256, 0, stream>>>(x, hbS, W1s, W2s, wf);

  int nwin = (NN + 63) / 64;   // 1563
  for (int L = 0; L < 3; L++) {
    k_agg <<<nwin * 8, 256, 0, stream>>>(hbS, rowptr, csr, AGG);
    k_mlp1<<<nwin, 256, 0, stream>>>(hbS, AGG, zbw,
                                     wf + (size_t)(L * 2) * 4096,
                                     b1s + L * 64, stats + L * 256);
    k_mlp2<<<nwin, 256, 0, stream>>>(zbw, stats + L * 256,
                                     gms + L * 64, bts + L * 64,
                                     wf + (size_t)(L * 2 + 1) * 4096,
                                     b2s + L * 64, hbS, out, Wd, bd,
                                     (L < 2) ? 1 : 0);
  }
}

// Round 8
// 398.586 us; speedup vs baseline: 1.2941x; 1.2941x over previous
//
#include <hip/hip_runtime.h>

#define NN 100000
#define EE 1600000
#define NPAD 100032          // NN rounded up to 64-row MFMA tiles
#define NBKT 196             // ceil(NN/512) scatter buckets
#define CAP 9216             // bucket capacity (mean 8192, sigma 90 -> 11 sigma)
#define BN_EPS 1e-5f

using f32x4  = __attribute__((ext_vector_type(4))) float;
using f32x8  = __attribute__((ext_vector_type(8))) float;
using s16x8  = __attribute__((ext_vector_type(8))) short;
using u16x4  = __attribute__((ext_vector_type(4))) unsigned short;
using u16x8  = __attribute__((ext_vector_type(8))) unsigned short;
using bf16x8 = __attribute__((ext_vector_type(8))) __bf16;
typedef unsigned short ushort_t;

__device__ __forceinline__ float bf2f(ushort_t b) {
  union { unsigned u; float f; } x; x.u = ((unsigned)b) << 16; return x.f;
}
__device__ __forceinline__ ushort_t f2bf(float f) {
  union { float f; unsigned u; } x; x.f = f;
  unsigned r = x.u + 0x7fffu + ((x.u >> 16) & 1u);   // RN-even; no NaNs in pipeline
  return (ushort_t)(r >> 16);
}

// -------- merged k_bin + k_prep: blocks 0..781 bin (8 edges/thr),
//          782..7031 x->bf16, 7032..7044 W swizzle --------
__global__ __launch_bounds__(256) void k_binprep(
    const int* __restrict__ src, const int* __restrict__ dst,
    int* __restrict__ gbc, unsigned* __restrict__ ebuf,
    const float* __restrict__ x, ushort_t* __restrict__ hb,
    const float* __restrict__ W1s, const float* __restrict__ W2s,
    ushort_t* __restrict__ wf) {
  __shared__ int hist[NBKT];
  int b = blockIdx.x, t = threadIdx.x;
  if (b < 782) {
    for (int i = t; i < NBKT; i += 256) hist[i] = 0;
    __syncthreads();
    int base = b * 2048;
    int s[8], d[8];
#pragma unroll
    for (int j = 0; j < 8; j++) {
      int e = base + j * 256 + t;
      if (e < EE) { s[j] = src[e]; d[j] = dst[e]; atomicAdd(&hist[d[j] >> 9], 1); }
      else d[j] = -1;
    }
    __syncthreads();
    for (int i = t; i < NBKT; i += 256) {
      int c = hist[i];
      hist[i] = c ? atomicAdd(&gbc[i], c) : 0;   // reserve in-bucket run
    }
    __syncthreads();
#pragma unroll
    for (int j = 0; j < 8; j++) {
      if (d[j] >= 0) {
        int bkt = d[j] >> 9;
        int pos = atomicAdd(&hist[bkt], 1);
        if (pos < CAP)
          ebuf[(size_t)bkt * CAP + pos] = (unsigned)s[j] | ((unsigned)(d[j] & 511) << 17);
      }
    }
  } else if (b < 7032) {
    int i = (b - 782) * 256 + t;      // 4 elems of x each
    f32x4 v = *(const f32x4*)(x + (size_t)i * 4);
    u16x4 o;
#pragma unroll
    for (int m = 0; m < 4; m++) o[m] = f2bf(v[m]);
    *(u16x4*)(hb + (size_t)i * 4) = o;
  } else {
    int gid = (b - 7032) * 256 + t;
    if (gid >= 3072) return;          // 6 mats * 2u * 4t * 64 lanes
    int mat = gid >> 9, rem = gid & 511;
    int u = rem >> 8, tt = (rem >> 6) & 3, lane = rem & 63;
    const float* W = ((mat & 1) ? W2s : W1s) + (mat >> 1) * 4096;
    ushort_t* o = wf + gid * 8;
#pragma unroll
    for (int j = 0; j < 8; j++) {
      int k = u * 32 + (lane >> 4) * 8 + j;
      int n = tt * 16 + (lane & 15);
      o[j] = f2bf(W[k * 64 + n]);
    }
  }
}

// scan bucket counts -> ebase; rowptr[NN]=EE; zero BN stats
__global__ void k_bktscan(const int* __restrict__ gbc, int* __restrict__ ebase,
                          int* __restrict__ rowptr, float* __restrict__ stats) {
  __shared__ int sd[256];
  int t = threadIdx.x;
#pragma unroll
  for (int k = 0; k < 3; k++) stats[t + 256 * k] = 0.f;   // 768 floats
  int c = (t < NBKT) ? min(gbc[t], CAP) : 0;
  sd[t] = c; __syncthreads();
  for (int off = 1; off < 256; off <<= 1) {
    int x = 0;
    if (t >= off) x = sd[t - off];
    __syncthreads();
    sd[t] += x;
    __syncthreads();
  }
  if (t < NBKT) ebase[t] = sd[t] - c;          // exclusive
  if (t == NBKT - 1) rowptr[NN] = sd[t];       // == EE
}

// per bucket: LDS degree hist -> scan -> rowptr + fine scatter. 1024 threads
// (4x the old 256): the 196-block grid is <1 block/CU, so in-block parallelism
// is the only lever here.
__global__ __launch_bounds__(1024) void k_fine(const unsigned* __restrict__ ebuf,
                                               const int* __restrict__ gbc,
                                               const int* __restrict__ ebase,
                                               int* __restrict__ rowptr,
                                               int* __restrict__ csr) {
  __shared__ int dcur[512];
  __shared__ int sd[256];
  int b = blockIdx.x, t = threadIdx.x;
  int cnt = min(gbc[b], CAP);
  int eb = ebase[b];
  const unsigned* eb_p = ebuf + (size_t)b * CAP;
  if (t < 512) dcur[t] = 0;
  __syncthreads();
  for (int e = t; e < cnt; e += 1024)
    atomicAdd(&dcur[(eb_p[e] >> 17) & 511], 1);
  __syncthreads();
  int a0 = 0, a1 = 0, ps = 0;
  if (t < 256) { a0 = dcur[2 * t]; a1 = dcur[2 * t + 1]; ps = a0 + a1; sd[t] = ps; }
  __syncthreads();
  for (int off = 1; off < 256; off <<= 1) {
    int x = 0;
    if (t < 256 && t >= off) x = sd[t - off];
    __syncthreads();
    if (t < 256) sd[t] += x;
    __syncthreads();
  }
  if (t < 256) {
    int g0 = eb + sd[t] - ps;                  // global csr start for local node 2t
    dcur[2 * t] = g0; dcur[2 * t + 1] = g0 + a0;
    int n = (b << 9) + 2 * t;
    if (n < NN) rowptr[n] = g0;
    if (n + 1 < NN) rowptr[n + 1] = g0 + a0;
  }
  __syncthreads();
  for (int e = t; e < cnt; e += 1024) {
    unsigned v = eb_p[e];
    int pos = atomicAdd(&dcur[(v >> 17) & 511], 1);
    csr[pos] = (int)(v & 0x1FFFFu);
  }
}

// ---------------- k_gat (v8): lean barrier-free gather ----------------
// 256 thr = 32 groups of 8 lanes; group owns ONE node, full 128B rows
// (R2's line-efficient geometry) in R7's kernel shape: no LDS, no barriers,
// no MFMA phase -> max occupancy + max line rate. 8-deep unroll, csr indices
// for chunk k+1 prefetched while chunk k's rows are in flight; clamp-masked
// tail (weights in {0,1}, exact). Output: self+sum as bf16 (same rounding
// point as R2, which converted to bf16 before MFMA).
__global__ __launch_bounds__(256) void k_gat(
    const ushort_t* __restrict__ hb, const int* __restrict__ rowptr,
    const int* __restrict__ csr, ushort_t* __restrict__ aggb) {
  int tid = threadIdx.x;
  int grp = tid >> 3, fl = tid & 7;
  int node = blockIdx.x * 32 + grp;            // grid 3125*32 == NN exactly
  if (node >= NN) return;
  const ushort_t* hbase = hb + fl * 8;
  f32x8 A;
  {
    u16x8 sr = *(const u16x8*)(hbase + (size_t)node * 64);
#pragma unroll
    for (int m = 0; m < 8; m++) A[m] = bf2f(sr[m]);
  }
  int e = rowptr[node];
  int rem = rowptr[node + 1] - e;
  if (rem >= 8) {
    int s0 = csr[e],     s1 = csr[e + 1], s2 = csr[e + 2], s3 = csr[e + 3];
    int s4 = csr[e + 4], s5 = csr[e + 5], s6 = csr[e + 6], s7 = csr[e + 7];
    for (;;) {
      u16x8 r0 = *(const u16x8*)(hbase + (size_t)s0 * 64);
      u16x8 r1 = *(const u16x8*)(hbase + (size_t)s1 * 64);
      u16x8 r2 = *(const u16x8*)(hbase + (size_t)s2 * 64);
      u16x8 r3 = *(const u16x8*)(hbase + (size_t)s3 * 64);
      u16x8 r4 = *(const u16x8*)(hbase + (size_t)s4 * 64);
      u16x8 r5 = *(const u16x8*)(hbase + (size_t)s5 * 64);
      u16x8 r6 = *(const u16x8*)(hbase + (size_t)s6 * 64);
      u16x8 r7 = *(const u16x8*)(hbase + (size_t)s7 * 64);
      e += 8; rem -= 8;
      bool more = (rem >= 8);
      if (more) {                              // prefetch next chunk's indices
        s0 = csr[e];     s1 = csr[e + 1]; s2 = csr[e + 2]; s3 = csr[e + 3];
        s4 = csr[e + 4]; s5 = csr[e + 5]; s6 = csr[e + 6]; s7 = csr[e + 7];
      }
#pragma unroll
      for (int m = 0; m < 8; m++) A[m] += bf2f(r0[m]);
#pragma unroll
      for (int m = 0; m < 8; m++) A[m] += bf2f(r1[m]);
#pragma unroll
      for (int m = 0; m < 8; m++) A[m] += bf2f(r2[m]);
#pragma unroll
      for (int m = 0; m < 8; m++) A[m] += bf2f(r3[m]);
#pragma unroll
      for (int m = 0; m < 8; m++) A[m] += bf2f(r4[m]);
#pragma unroll
      for (int m = 0; m < 8; m++) A[m] += bf2f(r5[m]);
#pragma unroll
      for (int m = 0; m < 8; m++) A[m] += bf2f(r6[m]);
#pragma unroll
      for (int m = 0; m < 8; m++) A[m] += bf2f(r7[m]);
      if (!more) break;
    }
  }
  if (rem > 0) {                               // clamp-masked tail (exact)
    int last = e + rem - 1;
    int s0 = csr[e];
    int s1 = csr[min(e + 1, last)], s2 = csr[min(e + 2, last)];
    int s3 = csr[min(e + 3, last)], s4 = csr[min(e + 4, last)];
    int s5 = csr[min(e + 5, last)], s6 = csr[min(e + 6, last)];
    int s7 = csr[min(e + 7, last)];
    u16x8 r0 = *(const u16x8*)(hbase + (size_t)s0 * 64);
    u16x8 r1 = *(const u16x8*)(hbase + (size_t)s1 * 64);
    u16x8 r2 = *(const u16x8*)(hbase + (size_t)s2 * 64);
    u16x8 r3 = *(const u16x8*)(hbase + (size_t)s3 * 64);
    u16x8 r4 = *(const u16x8*)(hbase + (size_t)s4 * 64);
    u16x8 r5 = *(const u16x8*)(hbase + (size_t)s5 * 64);
    u16x8 r6 = *(const u16x8*)(hbase + (size_t)s6 * 64);
    u16x8 r7 = *(const u16x8*)(hbase + (size_t)s7 * 64);
    float w1 = (rem > 1) ? 1.f : 0.f, w2 = (rem > 2) ? 1.f : 0.f;
    float w3 = (rem > 3) ? 1.f : 0.f, w4 = (rem > 4) ? 1.f : 0.f;
    float w5 = (rem > 5) ? 1.f : 0.f, w6 = (rem > 6) ? 1.f : 0.f;
    float w7 = (rem > 7) ? 1.f : 0.f;
#pragma unroll
    for (int m = 0; m < 8; m++) A[m] += bf2f(r0[m]);
#pragma unroll
    for (int m = 0; m < 8; m++) A[m] += w1 * bf2f(r1[m]);
#pragma unroll
    for (int m = 0; m < 8; m++) A[m] += w2 * bf2f(r2[m]);
#pragma unroll
    for (int m = 0; m < 8; m++) A[m] += w3 * bf2f(r3[m]);
#pragma unroll
    for (int m = 0; m < 8; m++) A[m] += w4 * bf2f(r4[m]);
#pragma unroll
    for (int m = 0; m < 8; m++) A[m] += w5 * bf2f(r5[m]);
#pragma unroll
    for (int m = 0; m < 8; m++) A[m] += w6 * bf2f(r6[m]);
#pragma unroll
    for (int m = 0; m < 8; m++) A[m] += w7 * bf2f(r7[m]);
  }
  u16x8 o;
#pragma unroll
  for (int m = 0; m < 8; m++) o[m] = f2bf(A[m]);
  *(u16x8*)(aggb + (size_t)node * 64 + fl * 8) = o;     // 128B/group coalesced
}

// ---------------- k_mlp1: z = aggb@W1 + b1; BN stats; zb bf16 ----------------
// Coalesced tile load, MFMA, epilogue restaged through LDS -> coalesced
// u16x8 stores (no scattered 2B stores).
__global__ __launch_bounds__(256) void k_mlp1(
    const ushort_t* __restrict__ aggb, ushort_t* __restrict__ zb,
    const ushort_t* __restrict__ wfrag, const float* __restrict__ b1,
    float* __restrict__ stats) {
  __shared__ __align__(16) ushort_t sw[64 * 72];
  __shared__ float lsum[64], lsq[64];
  int tid = threadIdx.x;
  if (tid < 64) lsum[tid] = 0.f;
  else if (tid < 128) lsq[tid - 64] = 0.f;
  {
    int r = tid >> 2, c0 = (tid & 3) * 16;
    size_t grow = (size_t)blockIdx.x * 64 + r;
    u16x8 v0 = {0, 0, 0, 0, 0, 0, 0, 0}, v1 = v0;
    if (grow < NN) {
      v0 = *(const u16x8*)(aggb + grow * 64 + c0);
      v1 = *(const u16x8*)(aggb + grow * 64 + c0 + 8);
    }
    *(u16x8*)(sw + r * 72 + c0) = v0;
    *(u16x8*)(sw + r * 72 + c0 + 8) = v1;
  }
  __syncthreads();
  int wv = tid >> 6, lane = tid & 63;
  int quad = lane >> 4, lo = lane & 15;
  s16x8 bfr[2][4];
#pragma unroll
  for (int u = 0; u < 2; u++)
#pragma unroll
    for (int t = 0; t < 4; t++)
      bfr[u][t] = *(const s16x8*)(wfrag + (size_t)((u * 4 + t) * 64 + lane) * 8);
  f32x4 acc[4] = {};
#pragma unroll
  for (int u = 0; u < 2; u++) {
    bf16x8 af = *(const bf16x8*)(sw + (wv * 16 + lo) * 72 + u * 32 + quad * 8);
#pragma unroll
    for (int t = 0; t < 4; t++)
      acc[t] = __builtin_amdgcn_mfma_f32_16x16x32_bf16(
          af, __builtin_bit_cast(bf16x8, bfr[u][t]), acc[t], 0, 0, 0);
  }
  int row0 = blockIdx.x * 64 + wv * 16;
  __syncthreads();                             // all MFMA reads of sw done
#pragma unroll
  for (int t = 0; t < 4; t++) {
    int col = t * 16 + lo;
    float bb = b1[col];
    float s1 = 0.f, s2 = 0.f;
#pragma unroll
    for (int r = 0; r < 4; r++) {
      int row = row0 + quad * 4 + r;
      if (row < NN) {
        float v = acc[t][r] + bb;
        sw[(wv * 16 + quad * 4 + r) * 72 + col] = f2bf(v);
        s1 += v; s2 += v * v;
      }
    }
    atomicAdd(&lsum[col], s1);
    atomicAdd(&lsq[col], s2);
  }
  __syncthreads();
  {
    int r = tid >> 2, c0 = (tid & 3) * 16;
    size_t grow = (size_t)blockIdx.x * 64 + r;
    if (grow < NN) {
      *(u16x8*)(zb + grow * 64 + c0)     = *(const u16x8*)(sw + r * 72 + c0);
      *(u16x8*)(zb + grow * 64 + c0 + 8) = *(const u16x8*)(sw + r * 72 + c0 + 8);
    }
  }
  if (tid < 64) {
    atomicAdd(&stats[tid], lsum[tid]);
    atomicAdd(&stats[64 + tid], lsq[tid]);
  }
}

// relu_out=1 (L0,L1): hb16 = relu( relu(zb*a+c)@W2 + b2 )
// relu_out=0 (L2):    h -> out+200000 (fp32) AND out[0..2N) = h@Wd + bd
// Epilogues restaged through LDS -> coalesced stores.
__global__ __launch_bounds__(256) void k_mlp2(
    const ushort_t* __restrict__ zb, const float* __restrict__ stats,
    const float* __restrict__ gamma, const float* __restrict__ beta,
    const ushort_t* __restrict__ wfrag, const float* __restrict__ b2,
    ushort_t* __restrict__ hb, float* __restrict__ out,
    const float* __restrict__ Wd, const float* __restrict__ bd, int relu_out) {
  __shared__ __align__(16) ushort_t sw[64 * 72];
  __shared__ __align__(16) float swf[64 * 68];     // f32 restage (decoder path)
  __shared__ float abn[64], cbn[64];
  int tid = threadIdx.x;
  if (tid < 64) {   // fused BN finalize
    float inv = 1.f / (float)NN;
    float mu = stats[tid] * inv;
    float var = stats[64 + tid] * inv - mu * mu;
    float a = gamma[tid] * rsqrtf(var + BN_EPS);
    abn[tid] = a;
    cbn[tid] = beta[tid] - mu * a;
  }
  __syncthreads();
  {   // phase 1: BN affine + ReLU on bf16 z -> bf16 tile in LDS
    int r = tid >> 2, c0 = (tid & 3) * 16;
    size_t grow = (size_t)blockIdx.x * 64 + r;     // < NPAD; padded rows masked later
#pragma unroll
    for (int jj = 0; jj < 16; jj += 8) {
      s16x8 zv = *(const s16x8*)(zb + grow * 64 + c0 + jj);
      f32x4 av0 = *(const f32x4*)(abn + c0 + jj);
      f32x4 av1 = *(const f32x4*)(abn + c0 + jj + 4);
      f32x4 cv0 = *(const f32x4*)(cbn + c0 + jj);
      f32x4 cv1 = *(const f32x4*)(cbn + c0 + jj + 4);
#pragma unroll
      for (int m = 0; m < 4; m++) {
        float v0 = fmaxf(bf2f((ushort_t)zv[m]) * av0[m] + cv0[m], 0.f);
        float v1 = fmaxf(bf2f((ushort_t)zv[m + 4]) * av1[m] + cv1[m], 0.f);
        sw[r * 72 + c0 + jj + m] = f2bf(v0);
        sw[r * 72 + c0 + jj + m + 4] = f2bf(v1);
      }
    }
  }
  __syncthreads();
  int wv = tid >> 6, lane = tid & 63;
  int quad = lane >> 4, lo = lane & 15;

  s16x8 bfr[2][4];
#pragma unroll
  for (int u = 0; u < 2; u++)
#pragma unroll
    for (int t = 0; t < 4; t++)
      bfr[u][t] = *(const s16x8*)(wfrag + (size_t)((u * 4 + t) * 64 + lane) * 8);

  f32x4 acc[4] = {};
#pragma unroll
  for (int u = 0; u < 2; u++) {
    bf16x8 af = *(const bf16x8*)(sw + (wv * 16 + lo) * 72 + u * 32 + quad * 8);
#pragma unroll
    for (int t = 0; t < 4; t++)
      acc[t] = __builtin_amdgcn_mfma_f32_16x16x32_bf16(
          af, __builtin_bit_cast(bf16x8, bfr[u][t]), acc[t], 0, 0, 0);
  }
  int row0 = blockIdx.x * 64 + wv * 16;
  float bbv[4];
#pragma unroll
  for (int t = 0; t < 4; t++) bbv[t] = b2[t * 16 + lo];

  if (relu_out) {
    __syncthreads();                           // MFMA reads of sw done
#pragma unroll
    for (int t = 0; t < 4; t++) {
      int col = t * 16 + lo;
#pragma unroll
      for (int r = 0; r < 4; r++) {
        int row = row0 + quad * 4 + r;
        if (row < NN)
          sw[(wv * 16 + quad * 4 + r) * 72 + col] =
              f2bf(fmaxf(acc[t][r] + bbv[t], 0.f));
      }
    }
    __syncthreads();
    int r = tid >> 2, c0 = (tid & 3) * 16;
    size_t grow = (size_t)blockIdx.x * 64 + r;
    if (grow < NN) {
      *(u16x8*)(hb + grow * 64 + c0)     = *(const u16x8*)(sw + r * 72 + c0);
      *(u16x8*)(hb + grow * 64 + c0 + 8) = *(const u16x8*)(sw + r * 72 + c0 + 8);
    }
  } else {
    float* outh = out + (size_t)NN * 2;
    float wd0[4], wd1[4];
#pragma unroll
    for (int t = 0; t < 4; t++) {
      wd0[t] = Wd[(t * 16 + lo) * 2];
      wd1[t] = Wd[(t * 16 + lo) * 2 + 1];
    }
    float bd0 = bd[0], bd1 = bd[1];
#pragma unroll
    for (int t = 0; t < 4; t++) {
      int col = t * 16 + lo;
#pragma unroll
      for (int r = 0; r < 4; r++)
        swf[(wv * 16 + quad * 4 + r) * 68 + col] = acc[t][r] + bbv[t];
    }
#pragma unroll
    for (int r = 0; r < 4; r++) {
      float p0 = 0.f, p1 = 0.f;
#pragma unroll
      for (int t = 0; t < 4; t++) {
        float v = acc[t][r] + bbv[t];
        p0 += v * wd0[t]; p1 += v * wd1[t];
      }
#pragma unroll
      for (int o = 1; o < 16; o <<= 1) {   // reduce across the 16 lanes of the quad
        p0 += __shfl_xor(p0, o);
        p1 += __shfl_xor(p1, o);
      }
      int row = row0 + quad * 4 + r;
      if (lo == 0 && row < NN) {
        out[(size_t)row * 2 + 0] = p0 + bd0;
        out[(size_t)row * 2 + 1] = p1 + bd1;
      }
    }
    __syncthreads();                         // swf complete
#pragma unroll
    for (int it = 0; it < 4; it++) {
      int r = (tid >> 4) + it * 16, cseg = (tid & 15) * 4;
      size_t grow = (size_t)blockIdx.x * 64 + r;
      if (grow < NN)
        *(f32x4*)(outh + grow * 64 + cseg) = *(const f32x4*)(swf + r * 68 + cseg);
    }
  }
}

extern "C" void kernel_launch(void* const* d_in, const int* in_sizes, int n_in,
                              void* d_out, int out_size, void* d_ws, size_t ws_size,
                              hipStream_t stream) {
  (void)in_sizes; (void)n_in; (void)out_size; (void)ws_size;
  const float* x   = (const float*)d_in[0];
  const int*   ei  = (const int*)d_in[1];
  const float* W1s = (const float*)d_in[2];
  const float* b1s = (const float*)d_in[3];
  const float* gms = (const float*)d_in[4];
  const float* bts = (const float*)d_in[5];
  const float* W2s = (const float*)d_in[6];
  const float* b2s = (const float*)d_in[7];
  const float* Wd  = (const float*)d_in[8];
  const float* bd  = (const float*)d_in[9];
  float* out = (float*)d_out;
  const int* src = ei;
  const int* dst = ei + EE;

  char* w = (char*)d_ws;
  size_t off = 0;
  auto alloc = [&](size_t b) { char* p = w + off; off += (b + 255) & ~(size_t)255; return p; };
  ushort_t* zb     = (ushort_t*)alloc((size_t)NPAD * 64 * 2);   // 12.8 MB (ebuf aliases)
  ushort_t* aggb   = (ushort_t*)alloc((size_t)NPAD * 64 * 2);   // 12.8 MB bf16 aggregates
  ushort_t* hb16   = (ushort_t*)alloc((size_t)NPAD * 64 * 2);   // 12.8 MB bf16 rows
  int*      csr    = (int*)alloc((size_t)EE * 4);               // 6.4 MB
  int*      rowptr = (int*)alloc((size_t)(NN + 1) * 4);
  int*      gbc    = (int*)alloc((size_t)NBKT * 4);
  int*      ebase  = (int*)alloc((size_t)NBKT * 4);
  float*    stats  = (float*)alloc(768 * 4);                    // 3 x [sum|sq|spare]
  ushort_t* wf     = (ushort_t*)alloc((size_t)6 * 512 * 8 * 2); // swizzled W frags
  unsigned* ebuf   = (unsigned*)zb;  // 196*9216*4 = 7.2 MB, used pre-mlp only

  hipMemsetAsync(gbc, 0, (size_t)NBKT * 4, stream);
  k_binprep<<<7045, 256, 0, stream>>>(src, dst, gbc, ebuf, x, hb16, W1s, W2s, wf);
  k_bktscan<<<1, 256, 0, stream>>>(gbc, ebase, rowptr, stats);
  k_fine   <<<NBKT, 1024, 0, stream>>>(ebuf, gbc, ebase, rowptr, csr);

  int nblk = (NN + 63) / 64;        // 1563
  for (int L = 0; L < 3; L++) {
    k_gat <<<(NN + 31) / 32, 256, 0, stream>>>(hb16, rowptr, csr, aggb);
    k_mlp1<<<nblk, 256, 0, stream>>>(aggb, zb,
                                     wf + (size_t)(L * 2) * 4096,
                                     b1s + L * 64, stats + L * 256);
    k_mlp2<<<nblk, 256, 0, stream>>>(zb, stats + L * 256,
                                     gms + L * 64, bts + L * 64,
                                     wf + (size_t)(L * 2 + 1) * 4096,
                                     b2s + L * 64, hb16, out, Wd, bd,
                                     (L < 2) ? 1 : 0);
  }
}

// Round 9
// 311.865 us; speedup vs baseline: 1.6540x; 1.2781x over previous
//
#include <hip/hip_runtime.h>

#define NN 100000
#define EE 1600000
#define NPAD 100032          // NN rounded up to 64-row MFMA tiles
#define NBKT 196             // ceil(NN/512) scatter buckets
#define CAP 9216             // bucket capacity (mean 8192, sigma 90 -> 11 sigma)
#define BN_EPS 1e-5f

using f32x4  = __attribute__((ext_vector_type(4))) float;
using f32x8  = __attribute__((ext_vector_type(8))) float;
using s16x8  = __attribute__((ext_vector_type(8))) short;
using u16x4  = __attribute__((ext_vector_type(4))) unsigned short;
using u16x8  = __attribute__((ext_vector_type(8))) unsigned short;
using bf16x8 = __attribute__((ext_vector_type(8))) __bf16;
typedef unsigned short ushort_t;

__device__ __forceinline__ float bf2f(ushort_t b) {
  union { unsigned u; float f; } x; x.u = ((unsigned)b) << 16; return x.f;
}
__device__ __forceinline__ ushort_t f2bf(float f) {
  union { float f; unsigned u; } x; x.f = f;
  unsigned r = x.u + 0x7fffu + ((x.u >> 16) & 1u);   // RN-even; no NaNs in pipeline
  return (ushort_t)(r >> 16);
}

// -------- merged k_bin + k_prep: blocks 0..781 bin (8 edges/thr),
//          782..7031 x->bf16, 7032..7044 W swizzle --------
__global__ __launch_bounds__(256) void k_binprep(
    const int* __restrict__ src, const int* __restrict__ dst,
    int* __restrict__ gbc, unsigned* __restrict__ ebuf,
    const float* __restrict__ x, ushort_t* __restrict__ hb,
    const float* __restrict__ W1s, const float* __restrict__ W2s,
    ushort_t* __restrict__ wf) {
  __shared__ int hist[NBKT];
  int b = blockIdx.x, t = threadIdx.x;
  if (b < 782) {
    for (int i = t; i < NBKT; i += 256) hist[i] = 0;
    __syncthreads();
    int base = b * 2048;
    int s[8], d[8];
#pragma unroll
    for (int j = 0; j < 8; j++) {
      int e = base + j * 256 + t;
      if (e < EE) { s[j] = src[e]; d[j] = dst[e]; atomicAdd(&hist[d[j] >> 9], 1); }
      else d[j] = -1;
    }
    __syncthreads();
    for (int i = t; i < NBKT; i += 256) {
      int c = hist[i];
      hist[i] = c ? atomicAdd(&gbc[i], c) : 0;   // reserve in-bucket run
    }
    __syncthreads();
#pragma unroll
    for (int j = 0; j < 8; j++) {
      if (d[j] >= 0) {
        int bkt = d[j] >> 9;
        int pos = atomicAdd(&hist[bkt], 1);
        if (pos < CAP)
          ebuf[(size_t)bkt * CAP + pos] = (unsigned)s[j] | ((unsigned)(d[j] & 511) << 17);
      }
    }
  } else if (b < 7032) {
    int i = (b - 782) * 256 + t;      // 4 elems of x each
    f32x4 v = *(const f32x4*)(x + (size_t)i * 4);
    u16x4 o;
#pragma unroll
    for (int m = 0; m < 4; m++) o[m] = f2bf(v[m]);
    *(u16x4*)(hb + (size_t)i * 4) = o;
  } else {
    int gid = (b - 7032) * 256 + t;
    if (gid >= 3072) return;          // 6 mats * 2u * 4t * 64 lanes
    int mat = gid >> 9, rem = gid & 511;
    int u = rem >> 8, tt = (rem >> 6) & 3, lane = rem & 63;
    const float* W = ((mat & 1) ? W2s : W1s) + (mat >> 1) * 4096;
    ushort_t* o = wf + gid * 8;
#pragma unroll
    for (int j = 0; j < 8; j++) {
      int k = u * 32 + (lane >> 4) * 8 + j;
      int n = tt * 16 + (lane & 15);
      o[j] = f2bf(W[k * 64 + n]);
    }
  }
}

// scan bucket counts -> ebase; rowptr[NN]=EE; zero BN stats
__global__ void k_bktscan(const int* __restrict__ gbc, int* __restrict__ ebase,
                          int* __restrict__ rowptr, float* __restrict__ stats) {
  __shared__ int sd[256];
  int t = threadIdx.x;
#pragma unroll
  for (int k = 0; k < 3; k++) stats[t + 256 * k] = 0.f;   // 768 floats
  int c = (t < NBKT) ? min(gbc[t], CAP) : 0;
  sd[t] = c; __syncthreads();
  for (int off = 1; off < 256; off <<= 1) {
    int x = 0;
    if (t >= off) x = sd[t - off];
    __syncthreads();
    sd[t] += x;
    __syncthreads();
  }
  if (t < NBKT) ebase[t] = sd[t] - c;          // exclusive
  if (t == NBKT - 1) rowptr[NN] = sd[t];       // == EE
}

// per bucket: LDS degree hist -> scan -> rowptr + fine scatter (1024 thr).
__global__ __launch_bounds__(1024) void k_fine(const unsigned* __restrict__ ebuf,
                                               const int* __restrict__ gbc,
                                               const int* __restrict__ ebase,
                                               int* __restrict__ rowptr,
                                               int* __restrict__ csr) {
  __shared__ int dcur[512];
  __shared__ int sd[256];
  int b = blockIdx.x, t = threadIdx.x;
  int cnt = min(gbc[b], CAP);
  int eb = ebase[b];
  const unsigned* eb_p = ebuf + (size_t)b * CAP;
  if (t < 512) dcur[t] = 0;
  __syncthreads();
  for (int e = t; e < cnt; e += 1024)
    atomicAdd(&dcur[(eb_p[e] >> 17) & 511], 1);
  __syncthreads();
  int a0 = 0, a1 = 0, ps = 0;
  if (t < 256) { a0 = dcur[2 * t]; a1 = dcur[2 * t + 1]; ps = a0 + a1; sd[t] = ps; }
  __syncthreads();
  for (int off = 1; off < 256; off <<= 1) {
    int x = 0;
    if (t < 256 && t >= off) x = sd[t - off];
    __syncthreads();
    if (t < 256) sd[t] += x;
    __syncthreads();
  }
  if (t < 256) {
    int g0 = eb + sd[t] - ps;                  // global csr start for local node 2t
    dcur[2 * t] = g0; dcur[2 * t + 1] = g0 + a0;
    int n = (b << 9) + 2 * t;
    if (n < NN) rowptr[n] = g0;
    if (n + 1 < NN) rowptr[n + 1] = g0 + a0;
  }
  __syncthreads();
  for (int e = t; e < cnt; e += 1024) {
    unsigned v = eb_p[e];
    int pos = atomicAdd(&dcur[(v >> 17) & 511], 1);
    csr[pos] = (int)(v & 0x1FFFFu);
  }
}

// ---------------- k_gat: lean barrier-free gather (proven R8 shape) ----------
__global__ __launch_bounds__(256) void k_gat(
    const ushort_t* __restrict__ hb, const int* __restrict__ rowptr,
    const int* __restrict__ csr, ushort_t* __restrict__ aggb) {
  int tid = threadIdx.x;
  int grp = tid >> 3, fl = tid & 7;
  int node = blockIdx.x * 32 + grp;            // grid 3125*32 == NN exactly
  if (node >= NN) return;
  const ushort_t* hbase = hb + fl * 8;
  f32x8 A;
  {
    u16x8 sr = *(const u16x8*)(hbase + (size_t)node * 64);
#pragma unroll
    for (int m = 0; m < 8; m++) A[m] = bf2f(sr[m]);
  }
  int e = rowptr[node];
  int rem = rowptr[node + 1] - e;
  if (rem >= 8) {
    int s0 = csr[e],     s1 = csr[e + 1], s2 = csr[e + 2], s3 = csr[e + 3];
    int s4 = csr[e + 4], s5 = csr[e + 5], s6 = csr[e + 6], s7 = csr[e + 7];
    for (;;) {
      u16x8 r0 = *(const u16x8*)(hbase + (size_t)s0 * 64);
      u16x8 r1 = *(const u16x8*)(hbase + (size_t)s1 * 64);
      u16x8 r2 = *(const u16x8*)(hbase + (size_t)s2 * 64);
      u16x8 r3 = *(const u16x8*)(hbase + (size_t)s3 * 64);
      u16x8 r4 = *(const u16x8*)(hbase + (size_t)s4 * 64);
      u16x8 r5 = *(const u16x8*)(hbase + (size_t)s5 * 64);
      u16x8 r6 = *(const u16x8*)(hbase + (size_t)s6 * 64);
      u16x8 r7 = *(const u16x8*)(hbase + (size_t)s7 * 64);
      e += 8; rem -= 8;
      bool more = (rem >= 8);
      if (more) {                              // prefetch next chunk's indices
        s0 = csr[e];     s1 = csr[e + 1]; s2 = csr[e + 2]; s3 = csr[e + 3];
        s4 = csr[e + 4]; s5 = csr[e + 5]; s6 = csr[e + 6]; s7 = csr[e + 7];
      }
#pragma unroll
      for (int m = 0; m < 8; m++) A[m] += bf2f(r0[m]);
#pragma unroll
      for (int m = 0; m < 8; m++) A[m] += bf2f(r1[m]);
#pragma unroll
      for (int m = 0; m < 8; m++) A[m] += bf2f(r2[m]);
#pragma unroll
      for (int m = 0; m < 8; m++) A[m] += bf2f(r3[m]);
#pragma unroll
      for (int m = 0; m < 8; m++) A[m] += bf2f(r4[m]);
#pragma unroll
      for (int m = 0; m < 8; m++) A[m] += bf2f(r5[m]);
#pragma unroll
      for (int m = 0; m < 8; m++) A[m] += bf2f(r6[m]);
#pragma unroll
      for (int m = 0; m < 8; m++) A[m] += bf2f(r7[m]);
      if (!more) break;
    }
  }
  if (rem > 0) {                               // clamp-masked tail (exact)
    int last = e + rem - 1;
    int s0 = csr[e];
    int s1 = csr[min(e + 1, last)], s2 = csr[min(e + 2, last)];
    int s3 = csr[min(e + 3, last)], s4 = csr[min(e + 4, last)];
    int s5 = csr[min(e + 5, last)], s6 = csr[min(e + 6, last)];
    int s7 = csr[min(e + 7, last)];
    u16x8 r0 = *(const u16x8*)(hbase + (size_t)s0 * 64);
    u16x8 r1 = *(const u16x8*)(hbase + (size_t)s1 * 64);
    u16x8 r2 = *(const u16x8*)(hbase + (size_t)s2 * 64);
    u16x8 r3 = *(const u16x8*)(hbase + (size_t)s3 * 64);
    u16x8 r4 = *(const u16x8*)(hbase + (size_t)s4 * 64);
    u16x8 r5 = *(const u16x8*)(hbase + (size_t)s5 * 64);
    u16x8 r6 = *(const u16x8*)(hbase + (size_t)s6 * 64);
    u16x8 r7 = *(const u16x8*)(hbase + (size_t)s7 * 64);
    float w1 = (rem > 1) ? 1.f : 0.f, w2 = (rem > 2) ? 1.f : 0.f;
    float w3 = (rem > 3) ? 1.f : 0.f, w4 = (rem > 4) ? 1.f : 0.f;
    float w5 = (rem > 5) ? 1.f : 0.f, w6 = (rem > 6) ? 1.f : 0.f;
    float w7 = (rem > 7) ? 1.f : 0.f;
#pragma unroll
    for (int m = 0; m < 8; m++) A[m] += bf2f(r0[m]);
#pragma unroll
    for (int m = 0; m < 8; m++) A[m] += w1 * bf2f(r1[m]);
#pragma unroll
    for (int m = 0; m < 8; m++) A[m] += w2 * bf2f(r2[m]);
#pragma unroll
    for (int m = 0; m < 8; m++) A[m] += w3 * bf2f(r3[m]);
#pragma unroll
    for (int m = 0; m < 8; m++) A[m] += w4 * bf2f(r4[m]);
#pragma unroll
    for (int m = 0; m < 8; m++) A[m] += w5 * bf2f(r5[m]);
#pragma unroll
    for (int m = 0; m < 8; m++) A[m] += w6 * bf2f(r6[m]);
#pragma unroll
    for (int m = 0; m < 8; m++) A[m] += w7 * bf2f(r7[m]);
  }
  u16x8 o;
#pragma unroll
  for (int m = 0; m < 8; m++) o[m] = f2bf(A[m]);
  *(u16x8*)(aggb + (size_t)node * 64 + fl * 8) = o;     // 128B/group coalesced
}

// ---------------- k_mlp1 (v2): 8 tiles/block; stats in regs; 196 blocks ----
// Cuts global stats atomics 8x (200K -> 25K, the R8 serializer) and amortizes
// weight-frag loads. Double LDS buffer (sw stage / swb epilogue) -> 2 barriers
// per tile.
__global__ __launch_bounds__(256) void k_mlp1(
    const ushort_t* __restrict__ aggb, ushort_t* __restrict__ zb,
    const ushort_t* __restrict__ wfrag, const float* __restrict__ b1,
    float* __restrict__ stats) {
  __shared__ __align__(16) ushort_t sw[64 * 72];
  __shared__ __align__(16) ushort_t swb[64 * 72];
  __shared__ float lsum[64], lsq[64];
  int tid = threadIdx.x;
  if (tid < 64) lsum[tid] = 0.f;
  else if (tid < 128) lsq[tid - 64] = 0.f;
  int wv = tid >> 6, lane = tid & 63;
  int quad = lane >> 4, lo = lane & 15;
  int rr = tid >> 2, c0 = (tid & 3) * 16;      // staging coords

  s16x8 bfr[2][4];
#pragma unroll
  for (int u = 0; u < 2; u++)
#pragma unroll
    for (int t = 0; t < 4; t++)
      bfr[u][t] = *(const s16x8*)(wfrag + (size_t)((u * 4 + t) * 64 + lane) * 8);
  float bbv[4], s1a[4] = {0.f, 0.f, 0.f, 0.f}, s2a[4] = {0.f, 0.f, 0.f, 0.f};
#pragma unroll
  for (int t = 0; t < 4; t++) bbv[t] = b1[t * 16 + lo];

  for (int it = 0; it < 8; it++) {
    int row0 = blockIdx.x * 512 + it * 64;
    {   // stage tile into sw
      size_t grow = (size_t)row0 + rr;
      u16x8 v0 = {0, 0, 0, 0, 0, 0, 0, 0}, v1 = v0;
      if (grow < NN) {
        v0 = *(const u16x8*)(aggb + grow * 64 + c0);
        v1 = *(const u16x8*)(aggb + grow * 64 + c0 + 8);
      }
      *(u16x8*)(sw + rr * 72 + c0) = v0;
      *(u16x8*)(sw + rr * 72 + c0 + 8) = v1;
    }
    __syncthreads();                           // sw ready; prev zb reads of swb done
    f32x4 acc[4] = {};
#pragma unroll
    for (int u = 0; u < 2; u++) {
      bf16x8 af = *(const bf16x8*)(sw + (wv * 16 + lo) * 72 + u * 32 + quad * 8);
#pragma unroll
      for (int t = 0; t < 4; t++)
        acc[t] = __builtin_amdgcn_mfma_f32_16x16x32_bf16(
            af, __builtin_bit_cast(bf16x8, bfr[u][t]), acc[t], 0, 0, 0);
    }
#pragma unroll
    for (int t = 0; t < 4; t++) {
      int col = t * 16 + lo;
      float s1 = 0.f, s2 = 0.f;
#pragma unroll
      for (int r = 0; r < 4; r++) {
        int row = row0 + quad * 4 + r;
        if (row < NN) {
          float v = acc[t][r] + bbv[t];
          swb[(wv * 16 + quad * 4 + r) * 72 + col] = f2bf(v);
          s1 += v; s2 += v * v;
        }
      }
      s1a[t] += s1; s2a[t] += s2;
    }
    __syncthreads();                           // swb complete
    {
      size_t grow = (size_t)row0 + rr;
      if (grow < NN) {
        *(u16x8*)(zb + grow * 64 + c0)     = *(const u16x8*)(swb + rr * 72 + c0);
        *(u16x8*)(zb + grow * 64 + c0 + 8) = *(const u16x8*)(swb + rr * 72 + c0 + 8);
      }
    }
  }
  // per-block stats reduce: 16 LDS atomics/col, then 128 global atomics/block
#pragma unroll
  for (int t = 0; t < 4; t++) {
    int col = t * 16 + lo;
    atomicAdd(&lsum[col], s1a[t]);
    atomicAdd(&lsq[col], s2a[t]);
  }
  __syncthreads();
  if (tid < 64) {
    atomicAdd(&stats[tid], lsum[tid]);
    atomicAdd(&stats[64 + tid], lsq[tid]);
  }
}

// relu_out=1 (L0,L1): hb16 = relu( relu(zb*a+c)@W2 + b2 )
// relu_out=0 (L2):    h -> out+200000 (fp32) AND out[0..2N) = h@Wd + bd
// Epilogues restaged through LDS -> coalesced stores.
__global__ __launch_bounds__(256) void k_mlp2(
    const ushort_t* __restrict__ zb, const float* __restrict__ stats,
    const float* __restrict__ gamma, const float* __restrict__ beta,
    const ushort_t* __restrict__ wfrag, const float* __restrict__ b2,
    ushort_t* __restrict__ hb, float* __restrict__ out,
    const float* __restrict__ Wd, const float* __restrict__ bd, int relu_out) {
  __shared__ __align__(16) ushort_t sw[64 * 72];
  __shared__ __align__(16) float swf[64 * 68];     // f32 restage (decoder path)
  __shared__ float abn[64], cbn[64];
  int tid = threadIdx.x;
  if (tid < 64) {   // fused BN finalize
    float inv = 1.f / (float)NN;
    float mu = stats[tid] * inv;
    float var = stats[64 + tid] * inv - mu * mu;
    float a = gamma[tid] * rsqrtf(var + BN_EPS);
    abn[tid] = a;
    cbn[tid] = beta[tid] - mu * a;
  }
  __syncthreads();
  {   // phase 1: BN affine + ReLU on bf16 z -> bf16 tile in LDS
    int r = tid >> 2, c0 = (tid & 3) * 16;
    size_t grow = (size_t)blockIdx.x * 64 + r;     // < NPAD; padded rows masked later
#pragma unroll
    for (int jj = 0; jj < 16; jj += 8) {
      s16x8 zv = *(const s16x8*)(zb + grow * 64 + c0 + jj);
      f32x4 av0 = *(const f32x4*)(abn + c0 + jj);
      f32x4 av1 = *(const f32x4*)(abn + c0 + jj + 4);
      f32x4 cv0 = *(const f32x4*)(cbn + c0 + jj);
      f32x4 cv1 = *(const f32x4*)(cbn + c0 + jj + 4);
#pragma unroll
      for (int m = 0; m < 4; m++) {
        float v0 = fmaxf(bf2f((ushort_t)zv[m]) * av0[m] + cv0[m], 0.f);
        float v1 = fmaxf(bf2f((ushort_t)zv[m + 4]) * av1[m] + cv1[m], 0.f);
        sw[r * 72 + c0 + jj + m] = f2bf(v0);
        sw[r * 72 + c0 + jj + m + 4] = f2bf(v1);
      }
    }
  }
  __syncthreads();
  int wv = tid >> 6, lane = tid & 63;
  int quad = lane >> 4, lo = lane & 15;

  s16x8 bfr[2][4];
#pragma unroll
  for (int u = 0; u < 2; u++)
#pragma unroll
    for (int t = 0; t < 4; t++)
      bfr[u][t] = *(const s16x8*)(wfrag + (size_t)((u * 4 + t) * 64 + lane) * 8);

  f32x4 acc[4] = {};
#pragma unroll
  for (int u = 0; u < 2; u++) {
    bf16x8 af = *(const bf16x8*)(sw + (wv * 16 + lo) * 72 + u * 32 + quad * 8);
#pragma unroll
    for (int t = 0; t < 4; t++)
      acc[t] = __builtin_amdgcn_mfma_f32_16x16x32_bf16(
          af, __builtin_bit_cast(bf16x8, bfr[u][t]), acc[t], 0, 0, 0);
  }
  int row0 = blockIdx.x * 64 + wv * 16;
  float bbv[4];
#pragma unroll
  for (int t = 0; t < 4; t++) bbv[t] = b2[t * 16 + lo];

  if (relu_out) {
    __syncthreads();                           // MFMA reads of sw done
#pragma unroll
    for (int t = 0; t < 4; t++) {
      int col = t * 16 + lo;
#pragma unroll
      for (int r = 0; r < 4; r++) {
        int row = row0 + quad * 4 + r;
        if (row < NN)
          sw[(wv * 16 + quad * 4 + r) * 72 + col] =
              f2bf(fmaxf(acc[t][r] + bbv[t], 0.f));
      }
    }
    __syncthreads();
    int r = tid >> 2, c0 = (tid & 3) * 16;
    size_t grow = (size_t)blockIdx.x * 64 + r;
    if (grow < NN) {
      *(u16x8*)(hb + grow * 64 + c0)     = *(const u16x8*)(sw + r * 72 + c0);
      *(u16x8*)(hb + grow * 64 + c0 + 8) = *(const u16x8*)(sw + r * 72 + c0 + 8);
    }
  } else {
    float* outh = out + (size_t)NN * 2;
    float wd0[4], wd1[4];
#pragma unroll
    for (int t = 0; t < 4; t++) {
      wd0[t] = Wd[(t * 16 + lo) * 2];
      wd1[t] = Wd[(t * 16 + lo) * 2 + 1];
    }
    float bd0 = bd[0], bd1 = bd[1];
#pragma unroll
    for (int t = 0; t < 4; t++) {
      int col = t * 16 + lo;
#pragma unroll
      for (int r = 0; r < 4; r++)
        swf[(wv * 16 + quad * 4 + r) * 68 + col] = acc[t][r] + bbv[t];
    }
#pragma unroll
    for (int r = 0; r < 4; r++) {
      float p0 = 0.f, p1 = 0.f;
#pragma unroll
      for (int t = 0; t < 4; t++) {
        float v = acc[t][r] + bbv[t];
        p0 += v * wd0[t]; p1 += v * wd1[t];
      }
#pragma unroll
      for (int o = 1; o < 16; o <<= 1) {   // reduce across the 16 lanes of the quad
        p0 += __shfl_xor(p0, o);
        p1 += __shfl_xor(p1, o);
      }
      int row = row0 + quad * 4 + r;
      if (lo == 0 && row < NN) {
        out[(size_t)row * 2 + 0] = p0 + bd0;
        out[(size_t)row * 2 + 1] = p1 + bd1;
      }
    }
    __syncthreads();                         // swf complete
#pragma unroll
    for (int it = 0; it < 4; it++) {
      int r = (tid >> 4) + it * 16, cseg = (tid & 15) * 4;
      size_t grow = (size_t)blockIdx.x * 64 + r;
      if (grow < NN)
        *(f32x4*)(outh + grow * 64 + cseg) = *(const f32x4*)(swf + r * 68 + cseg);
    }
  }
}

extern "C" void kernel_launch(void* const* d_in, const int* in_sizes, int n_in,
                              void* d_out, int out_size, void* d_ws, size_t ws_size,
                              hipStream_t stream) {
  (void)in_sizes; (void)n_in; (void)out_size; (void)ws_size;
  const float* x   = (const float*)d_in[0];
  const int*   ei  = (const int*)d_in[1];
  const float* W1s = (const float*)d_in[2];
  const float* b1s = (const float*)d_in[3];
  const float* gms = (const float*)d_in[4];
  const float* bts = (const float*)d_in[5];
  const float* W2s = (const float*)d_in[6];
  const float* b2s = (const float*)d_in[7];
  const float* Wd  = (const float*)d_in[8];
  const float* bd  = (const float*)d_in[9];
  float* out = (float*)d_out;
  const int* src = ei;
  const int* dst = ei + EE;

  char* w = (char*)d_ws;
  size_t off = 0;
  auto alloc = [&](size_t b) { char* p = w + off; off += (b + 255) & ~(size_t)255; return p; };
  ushort_t* zb     = (ushort_t*)alloc((size_t)NPAD * 64 * 2);   // 12.8 MB (ebuf aliases)
  ushort_t* aggb   = (ushort_t*)alloc((size_t)NPAD * 64 * 2);   // 12.8 MB bf16 aggregates
  ushort_t* hb16   = (ushort_t*)alloc((size_t)NPAD * 64 * 2);   // 12.8 MB bf16 rows
  int*      csr    = (int*)alloc((size_t)EE * 4);               // 6.4 MB
  int*      rowptr = (int*)alloc((size_t)(NN + 1) * 4);
  int*      gbc    = (int*)alloc((size_t)NBKT * 4);
  int*      ebase  = (int*)alloc((size_t)NBKT * 4);
  float*    stats  = (float*)alloc(768 * 4);                    // 3 x [sum|sq|spare]
  ushort_t* wf     = (ushort_t*)alloc((size_t)6 * 512 * 8 * 2); // swizzled W frags
  unsigned* ebuf   = (unsigned*)zb;  // 196*9216*4 = 7.2 MB, used pre-mlp only

  hipMemsetAsync(gbc, 0, (size_t)NBKT * 4, stream);
  k_binprep<<<7045, 256, 0, stream>>>(src, dst, gbc, ebuf, x, hb16, W1s, W2s, wf);
  k_bktscan<<<1, 256, 0, stream>>>(gbc, ebase, rowptr, stats);
  k_fine   <<<NBKT, 1024, 0, stream>>>(ebuf, gbc, ebase, rowptr, csr);

  int nblk = (NN + 63) / 64;        // 1563
  for (int L = 0; L < 3; L++) {
    k_gat <<<(NN + 31) / 32, 256, 0, stream>>>(hb16, rowptr, csr, aggb);
    k_mlp1<<<NBKT, 256, 0, stream>>>(aggb, zb,
                                     wf + (size_t)(L * 2) * 4096,
                                     b1s + L * 64, stats + L * 256);
    k_mlp2<<<nblk, 256, 0, stream>>>(zb, stats + L * 256,
                                     gms + L * 64, bts + L * 64,
                                     wf + (size_t)(L * 2 + 1) * 4096,
                                     b2s + L * 64, hb16, out, Wd, bd,
                                     (L < 2) ? 1 : 0);
  }
}